// Round 17
// baseline (3746.036 us; speedup 1.0000x reference)
//
#include <hip/hip_runtime.h>

typedef unsigned short u16;
typedef unsigned int u32;
typedef unsigned long long u64;
typedef float f4 __attribute__((ext_vector_type(4)));

#define NPTS 8192
#define SPTS 2048
#define KNS 32
#define MTOTF 524288.0f

// ---- d_out FLOAT32 ----
// O0 [0,49152) new_xyz | O1 [49152,98304) dup (sums scratch; restored by copy)
// O2 [98304,2195456) new_points (part/part2 scratch) | O3 [2195456,..) fps_idx
// ws: [0,1M) bq u16 | [1M,1.08M) WT weights transposed | [1.08M,..) ptsT f32/bf16
#define WT_OFF_F 262144
#define PT_OFF_B 1131520ull

__device__ __forceinline__ float bf2f(u16 u) { return __uint_as_float(((u32)u) << 16); }
__device__ __forceinline__ u16 f2bf(float f) {
  u32 u = __float_as_uint(f);
  return (u16)((u + 0x7FFFu + ((u >> 16) & 1u)) >> 16);
}
__device__ __forceinline__ f4 ld4(const float* p) { return *(const f4*)p; }
__device__ __forceinline__ void st4(float* p, f4 v) { *(f4*)p = v; }

// DPP wave64 max-reduce (u32, nonneg; identity 0). Result broadcast via readlane 63.
#define DPP_MAXSTEP(v, ctrl)                                                        \
  {                                                                                 \
    u32 _t = (u32)__builtin_amdgcn_update_dpp(0, (int)(v), ctrl, 0xf, 0xf, true);   \
    (v) = _t > (v) ? _t : (v);                                                      \
  }
__device__ __forceinline__ u32 wave_max_u32(u32 v) {
  DPP_MAXSTEP(v, 0x111);  // row_shr:1
  DPP_MAXSTEP(v, 0x112);  // row_shr:2
  DPP_MAXSTEP(v, 0x114);  // row_shr:4
  DPP_MAXSTEP(v, 0x118);  // row_shr:8
  DPP_MAXSTEP(v, 0x142);  // row_bcast:15
  DPP_MAXSTEP(v, 0x143);  // row_bcast:31
  return (u32)__builtin_amdgcn_readlane((int)v, 63);
}

// ================================================================ FPS
// 512 thr; coords in 16 named f4 regs (no arrays -> no scratch spill); (bd,bn)
// scalar tracking; two-phase DPP reduce; 1 barrier/iter; hist in LDS.
__global__ __launch_bounds__(512, 1) void fps_kernel(const float* __restrict__ xyz,
                                                     float* __restrict__ out) {
  __shared__ float4 hist[SPTS];   // 32 KB
  __shared__ u64 red[2][8];
  const int b = blockIdx.x, tid = threadIdx.x;
  const float* xp = xyz + (size_t)b * 3 * NPTS;
  const float* yp = xp + NPTS;
  const float* zp = xp + 2 * NPTS;
#define LD4S(V, base, g)                                                       \
  V.x = base[((g) * 4 + 0) * 512 + tid]; V.y = base[((g) * 4 + 1) * 512 + tid]; \
  V.z = base[((g) * 4 + 2) * 512 + tid]; V.w = base[((g) * 4 + 3) * 512 + tid];
  f4 X0, X1, X2, X3, Y0, Y1, Y2, Y3, Z0, Z1, Z2, Z3, D0, D1, D2, D3;
  LD4S(X0, xp, 0) LD4S(X1, xp, 1) LD4S(X2, xp, 2) LD4S(X3, xp, 3)
  LD4S(Y0, yp, 0) LD4S(Y1, yp, 1) LD4S(Y2, yp, 2) LD4S(Y3, yp, 3)
  LD4S(Z0, zp, 0) LD4S(Z1, zp, 1) LD4S(Z2, zp, 2) LD4S(Z3, zp, 3)
  f4 inf4 = {1e10f, 1e10f, 1e10f, 1e10f};
  D0 = inf4; D1 = inf4; D2 = inf4; D3 = inf4;
  int far = 0;
  for (int i = 0; i < SPTS; ++i) {
    float px = xp[far], py = yp[far], pz = zp[far];
    if (tid == 0) hist[i] = make_float4(px, py, pz, (float)far);
    float bd = -1.f;
    int bn = 0;
#define UPD(Xg, Yg, Zg, Dg, g, e, comp)                                              \
    {                                                                                \
      float dx = __fsub_rn(Xg.comp, px), dy = __fsub_rn(Yg.comp, py),                \
            dz = __fsub_rn(Zg.comp, pz);                                             \
      float d = __fadd_rn(__fadd_rn(__fmul_rn(dx, dx), __fmul_rn(dy, dy)),           \
                          __fmul_rn(dz, dz));                                        \
      float dm = fminf(Dg.comp, d);                                                  \
      Dg.comp = dm;                                                                  \
      bool c = dm > bd;                                                              \
      bd = c ? dm : bd;                                                              \
      bn = c ? (((g) * 4 + (e)) * 512 + tid) : bn;                                   \
    }
#define UPDG(Xg, Yg, Zg, Dg, g)                                                      \
    UPD(Xg, Yg, Zg, Dg, g, 0, x) UPD(Xg, Yg, Zg, Dg, g, 1, y)                        \
    UPD(Xg, Yg, Zg, Dg, g, 2, z) UPD(Xg, Yg, Zg, Dg, g, 3, w)
    UPDG(X0, Y0, Z0, D0, 0) UPDG(X1, Y1, Z1, D1, 1)
    UPDG(X2, Y2, Z2, D2, 2) UPDG(X3, Y3, Z3, D3, 3)
    u32 h = __float_as_uint(bd);
    u32 mh = wave_max_u32(h);
    u32 cand = (h == mh) ? (u32)(8191 - bn) : 0u;
    u32 ml = wave_max_u32(cand);
    if ((tid & 63) == 0) red[i & 1][tid >> 6] = ((u64)mh << 32) | ml;
    __syncthreads();
    const u64* r = red[i & 1];
    u64 m01 = r[0] > r[1] ? r[0] : r[1];
    u64 m23 = r[2] > r[3] ? r[2] : r[3];
    u64 m45 = r[4] > r[5] ? r[4] : r[5];
    u64 m67 = r[6] > r[7] ? r[6] : r[7];
    u64 ma = m01 > m23 ? m01 : m23;
    u64 mb = m45 > m67 ? m45 : m67;
    u64 bb = ma > mb ? ma : mb;
    far = (8191 - (int)(u32)(bb & 0xffffffffu)) & 8191;
  }
  __syncthreads();
  for (int i = tid; i < SPTS; i += 512) {
    float4 h = hist[i];
    out[(b * 3 + 0) * SPTS + i] = h.x;
    out[(b * 3 + 1) * SPTS + i] = h.y;
    out[(b * 3 + 2) * SPTS + i] = h.z;
    out[2195456 + b * SPTS + i] = h.w;
  }
}

// ================================================================ ball query
__global__ __launch_bounds__(256) void bq_kernel(const float* __restrict__ xyz,
                                                 const float* __restrict__ out3,
                                                 u16* __restrict__ bqStore) {
  const int wid = blockIdx.x * 4 + (threadIdx.x >> 6);
  const int lane = threadIdx.x & 63;
  const int b = wid >> 11;
  const int ctr = ((int)out3[wid]) & 8191;
  const float* xp = xyz + (size_t)b * 3 * NPTS;
  const float cx = xp[ctr], cy = xp[NPTS + ctr], cz = xp[2 * NPTS + ctr];
  int cnt = 0, first = 0;
  bool hf = false;
  for (int ch = 0; ch < NPTS / 64; ++ch) {
    int n = ch * 64 + lane;
    float dx = __fsub_rn(xp[n], cx);
    float dy = __fsub_rn(xp[NPTS + n], cy);
    float dz = __fsub_rn(xp[2 * NPTS + n], cz);
    float d2 = __fadd_rn(__fadd_rn(__fmul_rn(dx, dx), __fmul_rn(dy, dy)), __fmul_rn(dz, dz));
    bool inb = (d2 <= 0.25f);
    u64 m = __ballot(inb);
    if (m) {
      if (!hf) { first = ch * 64 + (__ffsll((unsigned long long)m) - 1); hf = true; }
      int pos = cnt + (int)__popcll(m & ((1ull << lane) - 1ull));
      if (inb && pos < KNS) bqStore[(size_t)wid * KNS + pos] = (u16)n;
      cnt += (int)__popcll(m);
      if (cnt >= KNS) break;
    }
  }
  if (cnt < KNS) {
    int slot = cnt + lane;
    if (slot < KNS) bqStore[(size_t)wid * KNS + slot] = (u16)first;
  }
}

// ================================================================ weight transpose prep
__global__ __launch_bounds__(256) void wt_prep(const float* __restrict__ W0,
                                               const float* __restrict__ W1,
                                               const float* __restrict__ W2,
                                               float* __restrict__ WT) {
  int i = blockIdx.x * 256 + threadIdx.x;
  if (i < 4352) {
    int c = i >> 6, o = i & 63;
    WT[i] = (c < 3) ? W0[o * 131 + c] : (c == 3 ? 0.f : W0[o * 131 + c - 1]);
  } else if (i < 8448) {
    int j = i - 4352, c = j >> 6, o = j & 63;
    WT[i] = W0[o * 131 + 67 + c];
  } else if (i < 12544) {
    int j = i - 8448, c = j >> 6, o = j & 63;
    WT[i] = W1[o * 64 + c];
  } else if (i < 20736) {
    int j = i - 12544, c = j >> 7, o = j & 127;
    WT[i] = W2[o * 64 + c];
  }
}

// ================================================================ transposes (pts)
__global__ __launch_bounds__(256) void ptsT_f32(const float* __restrict__ pts,
                                                float* __restrict__ ptsT) {
  __shared__ float tile[64][65];
  const int b = blockIdx.x >> 7, n0 = (blockIdx.x & 127) * 64, tid = threadIdx.x;
  {
    int nn = tid & 63;
#pragma unroll
    for (int p = 0; p < 16; ++p) {
      int c = p * 4 + (tid >> 6);
      tile[c][nn] = pts[((size_t)(b * 64 + c)) * NPTS + n0 + nn];
    }
  }
  __syncthreads();
  {
    int c = tid & 63;
#pragma unroll
    for (int p = 0; p < 16; ++p) {
      int nn = p * 4 + (tid >> 6);
      ptsT[((size_t)(b * NPTS) + n0 + nn) * 64 + c] = tile[c][nn];
    }
  }
}
__global__ __launch_bounds__(256) void ptsT_b16(const float* __restrict__ pts,
                                                u16* __restrict__ ptsTh) {
  __shared__ float tile[64][65];
  const int b = blockIdx.x >> 7, n0 = (blockIdx.x & 127) * 64, tid = threadIdx.x;
  {
    int nn = tid & 63;
#pragma unroll
    for (int p = 0; p < 16; ++p) {
      int c = p * 4 + (tid >> 6);
      tile[c][nn] = pts[((size_t)(b * 64 + c)) * NPTS + n0 + nn];
    }
  }
  __syncthreads();
  {
    int c = tid & 63;
#pragma unroll
    for (int p = 0; p < 16; ++p) {
      int nn = p * 4 + (tid >> 6);
      ptsTh[((size_t)(b * NPTS) + n0 + nn) * 64 + c] = f2bf(tile[c][nn]);
    }
  }
}

// ================================================================ stage helpers
__device__ __forceinline__ void load_w0(const float* __restrict__ WT, float* wbuf, int tid) {
  for (int i = tid * 4; i < 8448; i += 512) st4(wbuf + i, ld4(WT + i));
}
__device__ __forceinline__ void load_w1(const float* __restrict__ WT, float* wbuf, int tid) {
  for (int i = tid * 4; i < 4096; i += 512) st4(wbuf + i, ld4(WT + 8448 + i));
}
__device__ __forceinline__ void load_w2(const float* __restrict__ WT, float* wbuf, int tid) {
  for (int i = tid * 4; i < 8192; i += 512) st4(wbuf + i, ld4(WT + 12544 + i));
}

__device__ __forceinline__ void gather_m(const float* __restrict__ xyz,
                                         const float* __restrict__ pts,
                                         const float* __restrict__ ptsT,
                                         const u16* __restrict__ ptsTh, int mode,
                                         const int* gidx, int b, int ctr,
                                         float* featb, float* cf, int tid) {
  const float* xp = xyz + (size_t)b * 3 * NPTS;
  if (tid < KNS) {
    int idx = gidx[tid];
    featb[tid * 68 + 0] = __fsub_rn(xp[idx], xp[ctr]);
    featb[tid * 68 + 1] = __fsub_rn(xp[NPTS + idx], xp[NPTS + ctr]);
    featb[tid * 68 + 2] = __fsub_rn(xp[2 * NPTS + idx], xp[2 * NPTS + ctr]);
    featb[tid * 68 + 3] = 0.f;
  }
  const int k = tid >> 2, q = tid & 3;
  if (mode == 2) {
    const f4* base = (const f4*)(ptsT + ((size_t)(b * NPTS) + gidx[k]) * 64 + q * 16);
#pragma unroll
    for (int j = 0; j < 4; ++j) st4(featb + k * 68 + 4 + q * 16 + 4 * j, base[j]);
    if (tid < 64) cf[tid] = ptsT[((size_t)(b * NPTS) + ctr) * 64 + tid];
  } else if (mode == 1) {
    const uint2* base = (const uint2*)(ptsTh + ((size_t)(b * NPTS) + gidx[k]) * 64 + q * 16);
#pragma unroll
    for (int j = 0; j < 4; ++j) {
      uint2 w = base[j];
      f4 v;
      v.x = bf2f((u16)(w.x & 0xFFFFu)); v.y = bf2f((u16)(w.x >> 16));
      v.z = bf2f((u16)(w.y & 0xFFFFu)); v.w = bf2f((u16)(w.y >> 16));
      st4(featb + k * 68 + 4 + q * 16 + 4 * j, v);
    }
    if (tid < 64) cf[tid] = bf2f(ptsTh[((size_t)(b * NPTS) + ctr) * 64 + tid]);
  } else {
    const float* base = pts + ((size_t)b * 64 + q * 16) * NPTS + gidx[k];
#pragma unroll
    for (int e = 0; e < 16; ++e)
      featb[k * 68 + 4 + q * 16 + e] = base[(size_t)e * NPTS];
    if (tid < 64) cf[tid] = pts[((size_t)b * 64 + tid) * NPTS + ctr];
  }
}

__device__ __forceinline__ void mm_pre0(const float* featb, const float* cf,
                                        const float* wbuf, int tid, f4 acc[4]) {
  const int o0 = (tid & 15) * 4, k0 = (tid >> 4) * 4;
  const float* wc = wbuf + 4352;
  f4 cd = {0.f, 0.f, 0.f, 0.f};
  for (int c = 0; c < 64; c += 4) {
    f4 cfv = ld4(cf + c);
    cd += ld4(wc + (c + 0) * 64 + o0) * cfv.x;
    cd += ld4(wc + (c + 1) * 64 + o0) * cfv.y;
    cd += ld4(wc + (c + 2) * 64 + o0) * cfv.z;
    cd += ld4(wc + (c + 3) * 64 + o0) * cfv.w;
  }
  acc[0] = cd; acc[1] = cd; acc[2] = cd; acc[3] = cd;
  for (int c = 0; c < 68; c += 4) {
    f4 w0 = ld4(wbuf + (c + 0) * 64 + o0), w1 = ld4(wbuf + (c + 1) * 64 + o0);
    f4 w2 = ld4(wbuf + (c + 2) * 64 + o0), w3 = ld4(wbuf + (c + 3) * 64 + o0);
#pragma unroll
    for (int kk = 0; kk < 4; ++kk) {
      f4 f = ld4(featb + (k0 + kk) * 68 + c);
      acc[kk] += w0 * f.x + w1 * f.y + w2 * f.z + w3 * f.w;
    }
  }
}

__device__ __forceinline__ void mm64(const float* actb, const float* wbuf,
                                     int tid, f4 acc[4]) {
  const int o0 = (tid & 15) * 4, k0 = (tid >> 4) * 4;
  f4 z = {0.f, 0.f, 0.f, 0.f};
  acc[0] = z; acc[1] = z; acc[2] = z; acc[3] = z;
  for (int c = 0; c < 64; c += 4) {
    f4 w0 = ld4(wbuf + (c + 0) * 64 + o0), w1 = ld4(wbuf + (c + 1) * 64 + o0);
    f4 w2 = ld4(wbuf + (c + 2) * 64 + o0), w3 = ld4(wbuf + (c + 3) * 64 + o0);
#pragma unroll
    for (int kk = 0; kk < 4; ++kk) {
      f4 f = ld4(actb + (k0 + kk) * 68 + c);
      acc[kk] += w0 * f.x + w1 * f.y + w2 * f.z + w3 * f.w;
    }
  }
}

__device__ __forceinline__ f4 relu4(f4 v) {
  f4 r;
  r.x = fmaxf(v.x, 0.f); r.y = fmaxf(v.y, 0.f);
  r.z = fmaxf(v.z, 0.f); r.w = fmaxf(v.w, 0.f);
  return r;
}

__device__ __forceinline__ void bn_consts(const float* __restrict__ sums,
                                          const float* __restrict__ g, const float* __restrict__ b,
                                          float* sc, float* sh, int tid) {
  if (tid < 64) {
    const float invM = 1.0f / MTOTF;
    float mu = sums[tid] * invM;
    float var = fmaxf(sums[64 + tid] * invM - mu * mu, 0.f);
    float inv = rsqrtf(var + 1e-5f);
    float gg = g[tid], bb = b[tid];
    sc[tid] = gg * inv;
    sh[tid] = bb - gg * mu * inv;
  }
}

__device__ __forceinline__ void merge64(f4 s4, f4 q4, float (*sred)[64],
                                        float (*qred)[64], float* __restrict__ part,
                                        int blk, int tid) {
  const int o0 = (tid & 15) * 4;
  float s[4] = {s4.x, s4.y, s4.z, s4.w};
  float q[4] = {q4.x, q4.y, q4.z, q4.w};
#pragma unroll
  for (int m = 16; m <= 32; m <<= 1)
#pragma unroll
    for (int oo = 0; oo < 4; ++oo) {
      s[oo] += __shfl_xor(s[oo], m);
      q[oo] += __shfl_xor(q[oo], m);
    }
  if ((tid & 48) == 0) {
    int wv = tid >> 6;
#pragma unroll
    for (int oo = 0; oo < 4; ++oo) { sred[wv][o0 + oo] = s[oo]; qred[wv][o0 + oo] = q[oo]; }
  }
  __syncthreads();
  if (tid < 64) {
    part[(size_t)blk * 128 + tid] = sred[0][tid] + sred[1][tid];
    part[(size_t)blk * 128 + 64 + tid] = qred[0][tid] + qred[1][tid];
  }
}

// ================================================================ stage A
__global__ __launch_bounds__(128) void stageA_kernel(
    const float* __restrict__ xyz, const float* __restrict__ pts,
    const float* __restrict__ ptsT, const u16* __restrict__ ptsTh, int mode,
    const float* __restrict__ WT,
    const float* __restrict__ out3, const u16* __restrict__ bqStore, float* __restrict__ part) {
  __shared__ float wbuf[8448];
  __shared__ float featb[2176];
  __shared__ float cf[64];
  __shared__ float sred[2][64], qred[2][64];
  __shared__ int gidx[KNS];
  __shared__ int ctrS;
  const int tid = threadIdx.x;
  f4 s = {0.f, 0.f, 0.f, 0.f}, q = {0.f, 0.f, 0.f, 0.f};
  load_w0(WT, wbuf, tid);
  for (int it = 0; it < 8; ++it) {
    int bs = blockIdx.x * 8 + it, b = bs >> 11;
    __syncthreads();
    if (tid < KNS) gidx[tid] = bqStore[(size_t)bs * KNS + tid];
    if (tid == 127) ctrS = ((int)out3[bs]) & 8191;
    __syncthreads();
    gather_m(xyz, pts, ptsT, ptsTh, mode, gidx, b, ctrS, featb, cf, tid);
    __syncthreads();
    f4 acc[4];
    mm_pre0(featb, cf, wbuf, tid, acc);
#pragma unroll
    for (int kk = 0; kk < 4; ++kk) { s += acc[kk]; q += acc[kk] * acc[kk]; }
  }
  merge64(s, q, sred, qred, part, blockIdx.x, tid);
}

// ================================================================ stage B
__global__ __launch_bounds__(128) void stageB_kernel(
    const float* __restrict__ xyz, const float* __restrict__ pts,
    const float* __restrict__ ptsT, const u16* __restrict__ ptsTh, int mode,
    const float* __restrict__ WT,
    const float* __restrict__ out3, const u16* __restrict__ bqStore,
    const float* __restrict__ sums0, const float* __restrict__ g0, const float* __restrict__ b0,
    float* __restrict__ part) {
  __shared__ float wbuf[8448];
  __shared__ float featb[2176];
  __shared__ float cf[64];
  __shared__ float sc0[64], sh0[64];
  __shared__ float sred[2][64], qred[2][64];
  __shared__ int gidx[KNS];
  __shared__ int ctrS;
  const int tid = threadIdx.x;
  const int o0 = (tid & 15) * 4, k0 = (tid >> 4) * 4;
  f4 s = {0.f, 0.f, 0.f, 0.f}, q = {0.f, 0.f, 0.f, 0.f};
  bn_consts(sums0, g0, b0, sc0, sh0, tid);
  for (int it = 0; it < 8; ++it) {
    int bs = blockIdx.x * 8 + it, b = bs >> 11;
    __syncthreads();
    if (tid < KNS) gidx[tid] = bqStore[(size_t)bs * KNS + tid];
    if (tid == 127) ctrS = ((int)out3[bs]) & 8191;
    __syncthreads();
    load_w0(WT, wbuf, tid);
    gather_m(xyz, pts, ptsT, ptsTh, mode, gidx, b, ctrS, featb, cf, tid);
    __syncthreads();
    f4 acc[4];
    mm_pre0(featb, cf, wbuf, tid, acc);
    __syncthreads();
    f4 scv = ld4(sc0 + o0), shv = ld4(sh0 + o0);
#pragma unroll
    for (int kk = 0; kk < 4; ++kk)
      st4(featb + (k0 + kk) * 68 + o0, relu4(scv * acc[kk] + shv));
    load_w1(WT, wbuf, tid);
    __syncthreads();
    f4 acc2[4];
    mm64(featb, wbuf, tid, acc2);
#pragma unroll
    for (int kk = 0; kk < 4; ++kk) { s += acc2[kk]; q += acc2[kk] * acc2[kk]; }
  }
  merge64(s, q, sred, qred, part, blockIdx.x, tid);
}

// ================================================================ stage C
__global__ __launch_bounds__(128) void stageC_kernel(
    const float* __restrict__ xyz, const float* __restrict__ pts,
    const float* __restrict__ ptsT, const u16* __restrict__ ptsTh, int mode,
    const float* __restrict__ WT,
    const float* __restrict__ out3, const u16* __restrict__ bqStore,
    const float* __restrict__ sums0, const float* __restrict__ g0, const float* __restrict__ b0,
    const float* __restrict__ sums1, const float* __restrict__ g1, const float* __restrict__ b1,
    float* __restrict__ part) {
  __shared__ float wbuf[8448];
  __shared__ float featb[2176];
  __shared__ float cf[64];
  __shared__ float sc0[64], sh0[64], sc1[64], sh1[64];
  __shared__ float sred[2][128], qred[2][128];
  __shared__ int gidx[KNS];
  __shared__ int ctrS;
  const int tid = threadIdx.x;
  const int o0 = (tid & 15) * 4, k0 = (tid >> 4) * 4;
  const int p0 = (tid & 31) * 4, kq0 = (tid >> 5) * 8;
  f4 s = {0.f, 0.f, 0.f, 0.f}, q = {0.f, 0.f, 0.f, 0.f};
  bn_consts(sums0, g0, b0, sc0, sh0, tid);
  bn_consts(sums1, g1, b1, sc1, sh1, tid);
  for (int it = 0; it < 8; ++it) {
    int bs = blockIdx.x * 8 + it, b = bs >> 11;
    __syncthreads();
    if (tid < KNS) gidx[tid] = bqStore[(size_t)bs * KNS + tid];
    if (tid == 127) ctrS = ((int)out3[bs]) & 8191;
    __syncthreads();
    load_w0(WT, wbuf, tid);
    gather_m(xyz, pts, ptsT, ptsTh, mode, gidx, b, ctrS, featb, cf, tid);
    __syncthreads();
    f4 acc[4];
    mm_pre0(featb, cf, wbuf, tid, acc);
    __syncthreads();
    {
      f4 scv = ld4(sc0 + o0), shv = ld4(sh0 + o0);
#pragma unroll
      for (int kk = 0; kk < 4; ++kk)
        st4(featb + (k0 + kk) * 68 + o0, relu4(scv * acc[kk] + shv));
    }
    load_w1(WT, wbuf, tid);
    __syncthreads();
    f4 acc2[4];
    mm64(featb, wbuf, tid, acc2);
    __syncthreads();
    {
      f4 scv = ld4(sc1 + o0), shv = ld4(sh1 + o0);
#pragma unroll
      for (int kk = 0; kk < 4; ++kk)
        st4(featb + (k0 + kk) * 68 + o0, relu4(scv * acc2[kk] + shv));
    }
    load_w2(WT, wbuf, tid);
    __syncthreads();
    f4 a3[8];
    f4 z = {0.f, 0.f, 0.f, 0.f};
#pragma unroll
    for (int kk = 0; kk < 8; ++kk) a3[kk] = z;
    for (int c = 0; c < 64; c += 4) {
      f4 w0 = ld4(wbuf + (c + 0) * 128 + p0), w1 = ld4(wbuf + (c + 1) * 128 + p0);
      f4 w2 = ld4(wbuf + (c + 2) * 128 + p0), w3 = ld4(wbuf + (c + 3) * 128 + p0);
#pragma unroll
      for (int kk = 0; kk < 8; ++kk) {
        f4 f = ld4(featb + (kq0 + kk) * 68 + c);
        a3[kk] += w0 * f.x + w1 * f.y + w2 * f.z + w3 * f.w;
      }
    }
#pragma unroll
    for (int kk = 0; kk < 8; ++kk) { s += a3[kk]; q += a3[kk] * a3[kk]; }
  }
  {
    float sa[4] = {s.x, s.y, s.z, s.w}, qa[4] = {q.x, q.y, q.z, q.w};
#pragma unroll
    for (int oo = 0; oo < 4; ++oo) {
      sa[oo] += __shfl_xor(sa[oo], 32);
      qa[oo] += __shfl_xor(qa[oo], 32);
    }
    if ((tid & 32) == 0) {
      int wv = tid >> 6;
#pragma unroll
      for (int oo = 0; oo < 4; ++oo) { sred[wv][p0 + oo] = sa[oo]; qred[wv][p0 + oo] = qa[oo]; }
    }
  }
  __syncthreads();
  part[(size_t)blockIdx.x * 256 + tid] = sred[0][tid] + sred[1][tid];
  part[(size_t)blockIdx.x * 256 + 128 + tid] = qred[0][tid] + qred[1][tid];
}

// ================================================================ stage D
__global__ __launch_bounds__(128) void stageD_kernel(
    const float* __restrict__ xyz, const float* __restrict__ pts,
    const float* __restrict__ ptsT, const u16* __restrict__ ptsTh, int mode,
    const float* __restrict__ WT,
    const float* __restrict__ out3, const u16* __restrict__ bqStore,
    const float* __restrict__ sums0, const float* __restrict__ g0, const float* __restrict__ b0,
    const float* __restrict__ sums1, const float* __restrict__ g1, const float* __restrict__ b1,
    const float* __restrict__ sums2, const float* __restrict__ g2, const float* __restrict__ b2,
    float* __restrict__ out2) {
  __shared__ float wbuf[8448];
  __shared__ float featb[2176];
  __shared__ float cf[64];
  __shared__ float sc0[64], sh0[64], sc1[64], sh1[64];
  __shared__ float mxred[2][128], mnred[2][128];
  __shared__ int gidx[KNS];
  __shared__ int ctrS;
  const int bs = blockIdx.x, b = bs >> 11, sIdx = bs & 2047, tid = threadIdx.x;
  const int o0 = (tid & 15) * 4, k0 = (tid >> 4) * 4;
  const int p0 = (tid & 31) * 4, kq0 = (tid >> 5) * 8;
  bn_consts(sums0, g0, b0, sc0, sh0, tid);
  bn_consts(sums1, g1, b1, sc1, sh1, tid);
  if (tid < KNS) gidx[tid] = bqStore[(size_t)bs * KNS + tid];
  if (tid == 127) ctrS = ((int)out3[bs]) & 8191;
  __syncthreads();
  load_w0(WT, wbuf, tid);
  gather_m(xyz, pts, ptsT, ptsTh, mode, gidx, b, ctrS, featb, cf, tid);
  __syncthreads();
  f4 acc[4];
  mm_pre0(featb, cf, wbuf, tid, acc);
  __syncthreads();
  {
    f4 scv = ld4(sc0 + o0), shv = ld4(sh0 + o0);
#pragma unroll
    for (int kk = 0; kk < 4; ++kk)
      st4(featb + (k0 + kk) * 68 + o0, relu4(scv * acc[kk] + shv));
  }
  load_w1(WT, wbuf, tid);
  __syncthreads();
  f4 acc2[4];
  mm64(featb, wbuf, tid, acc2);
  __syncthreads();
  {
    f4 scv = ld4(sc1 + o0), shv = ld4(sh1 + o0);
#pragma unroll
    for (int kk = 0; kk < 4; ++kk)
      st4(featb + (k0 + kk) * 68 + o0, relu4(scv * acc2[kk] + shv));
  }
  load_w2(WT, wbuf, tid);
  __syncthreads();
  f4 a3[8];
  f4 z = {0.f, 0.f, 0.f, 0.f};
#pragma unroll
  for (int kk = 0; kk < 8; ++kk) a3[kk] = z;
  for (int c = 0; c < 64; c += 4) {
    f4 w0 = ld4(wbuf + (c + 0) * 128 + p0), w1 = ld4(wbuf + (c + 1) * 128 + p0);
    f4 w2 = ld4(wbuf + (c + 2) * 128 + p0), w3 = ld4(wbuf + (c + 3) * 128 + p0);
#pragma unroll
    for (int kk = 0; kk < 8; ++kk) {
      f4 f = ld4(featb + (kq0 + kk) * 68 + c);
      a3[kk] += w0 * f.x + w1 * f.y + w2 * f.z + w3 * f.w;
    }
  }
  float mx[4], mn[4];
#pragma unroll
  for (int oo = 0; oo < 4; ++oo) { mx[oo] = -3.4e38f; mn[oo] = 3.4e38f; }
#pragma unroll
  for (int kk = 0; kk < 8; ++kk) {
    float v[4] = {a3[kk].x, a3[kk].y, a3[kk].z, a3[kk].w};
#pragma unroll
    for (int oo = 0; oo < 4; ++oo) { mx[oo] = fmaxf(mx[oo], v[oo]); mn[oo] = fminf(mn[oo], v[oo]); }
  }
#pragma unroll
  for (int oo = 0; oo < 4; ++oo) {
    mx[oo] = fmaxf(mx[oo], __shfl_xor(mx[oo], 32));
    mn[oo] = fminf(mn[oo], __shfl_xor(mn[oo], 32));
  }
  if ((tid & 32) == 0) {
    int wv = tid >> 6;
#pragma unroll
    for (int oo = 0; oo < 4; ++oo) { mxred[wv][p0 + oo] = mx[oo]; mnred[wv][p0 + oo] = mn[oo]; }
  }
  __syncthreads();
  {
    float vmx = fmaxf(mxred[0][tid], mxred[1][tid]);
    float vmn = fminf(mnred[0][tid], mnred[1][tid]);
    const float invM = 1.0f / MTOTF;
    float mu = sums2[tid] * invM;
    float var = fmaxf(sums2[128 + tid] * invM - mu * mu, 0.f);
    float inv = rsqrtf(var + 1e-5f);
    float g = g2[tid], bb = b2[tid];
    float v = (g >= 0.f) ? vmx : vmn;
    float r = g * (v - mu) * inv + bb;
    r = fminf(fmaxf(r, 0.f), 100.f);
    out2[((size_t)(b * 128 + tid)) * SPTS + sIdx] = r;
  }
}

// ================================================================ reductions
__global__ void red1(const float* __restrict__ part, float* __restrict__ part2, int W) {
  const int tid = threadIdx.x;
  if (tid >= W) return;
  float a = 0.f;
  size_t r0 = (size_t)blockIdx.x * 32;
  for (int r = 0; r < 32; ++r) a += part[(r0 + r) * W + tid];
  part2[(size_t)blockIdx.x * W + tid] = a;
}
__global__ void red2(const float* __restrict__ part2, float* __restrict__ sums, int W) {
  const int tid = threadIdx.x;
  if (tid >= W) return;
  float a = 0.f;
  for (int j = 0; j < 64; ++j) a += part2[(size_t)j * W + tid];
  sums[tid] = a;
}

// ================================================================ final copy
__global__ __launch_bounds__(256) void copy_xyz(const float* __restrict__ src,
                                                float* __restrict__ dst) {
  int i = blockIdx.x * 256 + threadIdx.x;
  dst[i] = src[i];
}

// ================================================================ launcher
extern "C" void kernel_launch(void* const* d_in, const int* in_sizes, int n_in,
                              void* d_out, int out_size, void* d_ws, size_t ws_size,
                              hipStream_t stream) {
  (void)in_sizes; (void)n_in; (void)out_size;
  const float* xyz = (const float*)d_in[0];
  const float* pts = (const float*)d_in[1];
  const float* W0  = (const float*)d_in[2];
  const float* g0  = (const float*)d_in[3];
  const float* b0  = (const float*)d_in[4];
  const float* W1  = (const float*)d_in[5];
  const float* g1  = (const float*)d_in[6];
  const float* b1  = (const float*)d_in[7];
  const float* W2  = (const float*)d_in[8];
  const float* g2  = (const float*)d_in[9];
  const float* b2  = (const float*)d_in[10];
  float* out = (float*)d_out;

  u16*   bqStore = (u16*)d_ws;
  float* WT      = (float*)d_ws + WT_OFF_F;
  float* ptsT    = (float*)((char*)d_ws + PT_OFF_B);
  u16*   ptsTh   = (u16*) ((char*)d_ws + PT_OFF_B);
  int mode = 0;
  if (ws_size >= PT_OFF_B + 16777216)      mode = 2;
  else if (ws_size >= PT_OFF_B + 8388608)  mode = 1;

  float* sums0 = out + 49152;
  float* sums1 = out + 49152 + 128;
  float* sums2 = out + 49152 + 256;
  float* part  = out + 98304;
  float* part2 = out + 622592;
  float* out3  = out + 2195456;
  float* out2  = out + 98304;

  fps_kernel<<<8, 512, 0, stream>>>(xyz, out);
  wt_prep<<<81, 256, 0, stream>>>(W0, W1, W2, WT);
  if (mode == 2)      ptsT_f32<<<1024, 256, 0, stream>>>(pts, ptsT);
  else if (mode == 1) ptsT_b16<<<1024, 256, 0, stream>>>(pts, ptsTh);
  bq_kernel<<<4096, 256, 0, stream>>>(xyz, out3, bqStore);
  stageA_kernel<<<2048, 128, 0, stream>>>(xyz, pts, ptsT, ptsTh, mode, WT, out3, bqStore, part);
  red1<<<64, 256, 0, stream>>>(part, part2, 128);
  red2<<<1, 256, 0, stream>>>(part2, sums0, 128);
  stageB_kernel<<<2048, 128, 0, stream>>>(xyz, pts, ptsT, ptsTh, mode, WT, out3, bqStore,
                                          sums0, g0, b0, part);
  red1<<<64, 256, 0, stream>>>(part, part2, 128);
  red2<<<1, 256, 0, stream>>>(part2, sums1, 128);
  stageC_kernel<<<2048, 128, 0, stream>>>(xyz, pts, ptsT, ptsTh, mode, WT, out3, bqStore,
                                          sums0, g0, b0, sums1, g1, b1, part);
  red1<<<64, 256, 0, stream>>>(part, part2, 256);
  red2<<<1, 256, 0, stream>>>(part2, sums2, 256);
  stageD_kernel<<<16384, 128, 0, stream>>>(xyz, pts, ptsT, ptsTh, mode, WT, out3, bqStore,
                                           sums0, g0, b0, sums1, g1, b1,
                                           sums2, g2, b2, out2);
  copy_xyz<<<192, 256, 0, stream>>>(out, out + 49152);
}